// Round 1
// baseline (36629.202 us; speedup 1.0000x reference)
//
#include <hip/hip_runtime.h>
#include <cstddef>
#include <cstdint>

// Model dims (fixed by reference)
#define T_LEN 512
#define B_SZ  128
#define MD    31
#define E_SZ  256
#define H_SZ  512
#define S_SZ  128
#define GAMMA_F 1.0f
#define LOG001   -4.605170185988091f   // log(0.01)
#define HALF_L2PI 0.9189385332046727f  // 0.5*log(2*pi)

// ---------------- zero/init: h0 = 0, out = 0 (ws/out are poisoned 0xAA each run) ----------------
__global__ void zero_init(float* __restrict__ h0, float* __restrict__ out) {
    int i = blockIdx.x * blockDim.x + threadIdx.x;
    if (i < B_SZ * H_SZ) h0[i] = 0.f;
    if (i == 0) out[0] = 0.f;
}

// ---------------- pack W: wpack[col][768] = [W_hh[col][0:512] | W_ih[col][0:256]] ----------------
// col = gate*512 + j, gate order r,z,n (torch GRUCell layout)
__global__ void pack_w(const float* __restrict__ W_ih, const float* __restrict__ W_hh,
                       float* __restrict__ wpack) {
    const int n = 1536 * 768;
    for (int i = blockIdx.x * blockDim.x + threadIdx.x; i < n; i += gridDim.x * blockDim.x) {
        int col = i / 768, k = i - col * 768;
        wpack[i] = (k < 512) ? W_hh[col * 512 + k] : W_ih[col * 256 + (k - 512)];
    }
}

// ---------------- embed: phi[row][e] = relu(b_embed[e] + sum_m x[row][m]*W_embed[e][m]) ----------
__global__ __launch_bounds__(256) void embed_phi(
    const float* __restrict__ x, const float* __restrict__ W_embed,
    const float* __restrict__ b_embed, float* __restrict__ phi) {
    __shared__ float xs[8][32];
    const int e = threadIdx.x;  // 0..255, one output col per thread
    float w[MD];
    #pragma unroll
    for (int m = 0; m < MD; ++m) w[m] = W_embed[e * MD + m];
    const float be = b_embed[e];
    const int nblocks = (T_LEN * B_SZ) / 8;
    for (int rb = blockIdx.x; rb < nblocks; rb += gridDim.x) {
        const int r0 = rb * 8;
        if (threadIdx.x < 8 * MD)
            xs[threadIdx.x / MD][threadIdx.x % MD] = x[(size_t)r0 * MD + threadIdx.x];
        __syncthreads();
        #pragma unroll
        for (int i = 0; i < 8; ++i) {
            float acc = be;
            #pragma unroll
            for (int m = 0; m < MD; ++m) acc = fmaf(xs[i][m], w[m], acc);
            phi[(size_t)(r0 + i) * E_SZ + e] = fmaxf(acc, 0.f);
        }
        __syncthreads();
    }
}

// ---------------- one GRU step: fused (hg GEMM + xg GEMM + gates + h update) --------------------
// grid: (64 j-tiles of 8, 4 b-tiles of 32), block 256. One (b,j) cell per thread.
// pre_r/pre_z combine input+hidden parts (biases add); n keeps xn/hn separate: n = tanh(xn + r*hn)
__global__ __launch_bounds__(256) void gru_step(
    const float* __restrict__ wpack, const float* __restrict__ phi_t,
    const float* __restrict__ h_cur, float* __restrict__ h_nxt,
    float* __restrict__ hs_t,
    const float* __restrict__ b_ih, const float* __restrict__ b_hh) {
    const int jl = threadIdx.x & 7, bl = threadIdx.x >> 3;
    const int j = blockIdx.x * 8 + jl;     // hidden unit 0..511
    const int b = blockIdx.y * 32 + bl;    // batch 0..127
    const float* __restrict__ wr = wpack + (size_t)j * 768;
    const float* __restrict__ wz = wpack + (size_t)(512 + j) * 768;
    const float* __restrict__ wn = wpack + (size_t)(1024 + j) * 768;
    const float* __restrict__ hrow = h_cur + b * H_SZ;
    const float* __restrict__ prow = phi_t + b * E_SZ;
    float pr = 0.f, pz = 0.f, xn = 0.f, hn = 0.f;
    #pragma unroll 4
    for (int k = 0; k < H_SZ; k += 4) {
        const float4 h4 = *(const float4*)(hrow + k);
        const float4 a  = *(const float4*)(wr + k);
        const float4 c  = *(const float4*)(wz + k);
        const float4 d  = *(const float4*)(wn + k);
        pr = fmaf(a.x, h4.x, pr); pr = fmaf(a.y, h4.y, pr);
        pr = fmaf(a.z, h4.z, pr); pr = fmaf(a.w, h4.w, pr);
        pz = fmaf(c.x, h4.x, pz); pz = fmaf(c.y, h4.y, pz);
        pz = fmaf(c.z, h4.z, pz); pz = fmaf(c.w, h4.w, pz);
        hn = fmaf(d.x, h4.x, hn); hn = fmaf(d.y, h4.y, hn);
        hn = fmaf(d.z, h4.z, hn); hn = fmaf(d.w, h4.w, hn);
    }
    #pragma unroll 4
    for (int k = 0; k < E_SZ; k += 4) {
        const float4 p4 = *(const float4*)(prow + k);
        const float4 a  = *(const float4*)(wr + 512 + k);
        const float4 c  = *(const float4*)(wz + 512 + k);
        const float4 d  = *(const float4*)(wn + 512 + k);
        pr = fmaf(a.x, p4.x, pr); pr = fmaf(a.y, p4.y, pr);
        pr = fmaf(a.z, p4.z, pr); pr = fmaf(a.w, p4.w, pr);
        pz = fmaf(c.x, p4.x, pz); pz = fmaf(c.y, p4.y, pz);
        pz = fmaf(c.z, p4.z, pz); pz = fmaf(c.w, p4.w, pz);
        xn = fmaf(d.x, p4.x, xn); xn = fmaf(d.y, p4.y, xn);
        xn = fmaf(d.z, p4.z, xn); xn = fmaf(d.w, p4.w, xn);
    }
    pr += b_ih[j] + b_hh[j];
    pz += b_ih[512 + j] + b_hh[512 + j];
    xn += b_ih[1024 + j];
    hn += b_hh[1024 + j];
    const float r = 1.f / (1.f + expf(-pr));
    const float z = 1.f / (1.f + expf(-pz));
    const float n = tanhf(fmaf(r, hn, xn));
    const float hold = hrow[j];
    const float hnew = fmaf(z, hold - n, n);   // (1-z)*n + z*h
    h_nxt[b * H_SZ + j] = hnew;
    hs_t[b * H_SZ + j] = hold;                 // pre-update state (scan collects h, not h_new)
}

// ---------------- he + mu/logvar + loss, fused. 16 rows per block, rows t>=1 only --------------
__global__ __launch_bounds__(256) void he_loss(
    const float* __restrict__ hs, const float* __restrict__ W_he, const float* __restrict__ b_he,
    const float* __restrict__ W_mu, const float* __restrict__ b_mu,
    const float* __restrict__ W_lv, const float* __restrict__ b_lv,
    const float* __restrict__ h_inf, const float* __restrict__ time_inf,
    const float* __restrict__ base_int, const float* __restrict__ x,
    const float* __restrict__ t_in, const float* __restrict__ mask,
    float* __restrict__ out) {
    __shared__ float he_s[16][129];
    __shared__ float wmu_s[MD][129];
    __shared__ float wlv_s[MD][129];
    __shared__ float hinf_s[S_SZ];
    __shared__ float red[4];
    for (int i = threadIdx.x; i < MD * S_SZ; i += 256) {
        wmu_s[i / S_SZ][i % S_SZ] = W_mu[i];
        wlv_s[i / S_SZ][i % S_SZ] = W_lv[i];
    }
    if (threadIdx.x < S_SZ) hinf_s[threadIdx.x] = h_inf[threadIdx.x];
    __syncthreads();

    const int row0 = B_SZ + blockIdx.x * 16;   // skip t=0 (rows 0..127)
    // phase 1: he[r][c] = relu(W_he[c]·hs[row0+r] + b_he[c]), 8 rows per thread, c = tid&127
    {
        const int c = threadIdx.x & 127, rg = threadIdx.x >> 7;
        const float* __restrict__ wrow = W_he + (size_t)c * H_SZ;
        float acc[8];
        #pragma unroll
        for (int i = 0; i < 8; ++i) acc[i] = b_he[c];
        for (int k = 0; k < H_SZ; k += 4) {
            const float4 w4 = *(const float4*)(wrow + k);
            #pragma unroll
            for (int i = 0; i < 8; ++i) {
                const float4 h4 = *(const float4*)(hs + (size_t)(row0 + rg * 8 + i) * H_SZ + k);
                acc[i] = fmaf(w4.x, h4.x, acc[i]);
                acc[i] = fmaf(w4.y, h4.y, acc[i]);
                acc[i] = fmaf(w4.z, h4.z, acc[i]);
                acc[i] = fmaf(w4.w, h4.w, acc[i]);
            }
        }
        #pragma unroll
        for (int i = 0; i < 8; ++i) he_s[rg * 8 + i][c] = fmaxf(acc[i], 0.f);
    }
    __syncthreads();
    // phase 2: per row r (tid>>4), marker markers m = q, q+16 (q = tid&15); time-ll on q==0
    const int r = threadIdx.x >> 4, q = threadIdx.x & 15;
    const int row = row0 + r;
    const float mk = mask[row];
    float lacc = 0.f;
    #pragma unroll
    for (int pass = 0; pass < 2; ++pass) {
        const int m = q + pass * 16;
        if (m < MD) {
            float mu = b_mu[m], lv = b_lv[m];
            for (int c2 = 0; c2 < S_SZ; ++c2) {
                const float h = he_s[r][c2];
                mu = fmaf(h, wmu_s[m][c2], mu);
                lv = fmaf(h, wlv_s[m][c2], lv);
            }
            const float ls    = fmaxf(0.5f * lv, LOG001);  // log(max(exp(.5lv), 0.01))
            const float inv_s = expf(-ls);
            const float zz    = (x[(size_t)row * MD + m] - mu) * inv_s;
            lacc += (0.5f * zz * zz + ls + HALF_L2PI) * mk;  // -marker_ll contribution
        }
    }
    if (q == 0) {
        float past = 0.f;
        for (int c2 = 0; c2 < S_SZ; ++c2) past = fmaf(he_s[r][c2], hinf_s[c2], past);
        const float ti = time_inf[0], bi = base_int[0];
        const float dt = t_in[(size_t)row * 2 + 1];
        const float term1 = past + ti * dt + bi;
        const float tll = term1 + (expf(past + bi) - expf(term1)) / ti;
        lacc += GAMMA_F * (-tll) * mk;
    }
    // block reduce -> one atomic per block
    #pragma unroll
    for (int off = 32; off > 0; off >>= 1) lacc += __shfl_down(lacc, off, 64);
    if ((threadIdx.x & 63) == 0) red[threadIdx.x >> 6] = lacc;
    __syncthreads();
    if (threadIdx.x == 0) atomicAdd(out, red[0] + red[1] + red[2] + red[3]);
}

extern "C" void kernel_launch(void* const* d_in, const int* in_sizes, int n_in,
                              void* d_out, int out_size, void* d_ws, size_t ws_size,
                              hipStream_t stream) {
    const float* x       = (const float*)d_in[0];
    const float* t_in    = (const float*)d_in[1];
    const float* mask    = (const float*)d_in[2];
    const float* W_embed = (const float*)d_in[3];
    const float* b_embed = (const float*)d_in[4];
    const float* W_ih    = (const float*)d_in[5];
    const float* b_ih    = (const float*)d_in[6];
    const float* W_hh    = (const float*)d_in[7];
    const float* b_hh    = (const float*)d_in[8];
    const float* W_he    = (const float*)d_in[9];
    const float* b_he    = (const float*)d_in[10];
    const float* W_mu    = (const float*)d_in[11];
    const float* b_mu    = (const float*)d_in[12];
    const float* W_lv    = (const float*)d_in[13];
    const float* b_lv    = (const float*)d_in[14];
    const float* h_inf   = (const float*)d_in[15];
    const float* tinf    = (const float*)d_in[16];
    const float* bint    = (const float*)d_in[17];
    float* out = (float*)d_out;

    // ws layout (bytes): phi 67.1MB | hs 134.2MB | wpack 4.7MB | hA | hB  => 197MB total
    char* ws = (char*)d_ws;
    const size_t OFF_PHI = 0, OFF_HS = 67108864ull, OFF_WPACK = 201326592ull,
                 OFF_HA = 206045184ull, OFF_HB = 206307328ull, TOTAL = 206569472ull;
    if (ws_size < TOTAL) return;  // fail loudly (absmax = |ref|) rather than segfault
    float* phi   = (float*)(ws + OFF_PHI);
    float* hs    = (float*)(ws + OFF_HS);
    float* wpack = (float*)(ws + OFF_WPACK);
    float* hA    = (float*)(ws + OFF_HA);
    float* hB    = (float*)(ws + OFF_HB);

    zero_init<<<dim3((B_SZ * H_SZ + 255) / 256), 256, 0, stream>>>(hA, out);
    pack_w<<<dim3(512), 256, 0, stream>>>(W_ih, W_hh, wpack);
    embed_phi<<<dim3(1024), 256, 0, stream>>>(x, W_embed, b_embed, phi);
    for (int t = 0; t < T_LEN; ++t) {
        const float* hc = (t & 1) ? hB : hA;
        float* hn       = (t & 1) ? hA : hB;
        gru_step<<<dim3(64, 4), 256, 0, stream>>>(wpack, phi + (size_t)t * B_SZ * E_SZ,
                                                  hc, hn, hs + (size_t)t * B_SZ * H_SZ,
                                                  b_ih, b_hh);
    }
    he_loss<<<dim3((T_LEN - 1) * B_SZ / 16), 256, 0, stream>>>(
        hs, W_he, b_he, W_mu, b_mu, W_lv, b_lv, h_inf, tinf, bint, x, t_in, mask, out);
}